// Round 4
// baseline (39.964 us; speedup 1.0000x reference)
//
#include <hip/hip_runtime.h>
#include <math.h>

// ExpertRouter: B=8, N=4096, D=1024, E=2  -> rows = 32768
// Outputs (concatenated float32):
//   [0 .. 65535]        expert_weights  [rows,2]  (0/1)
//   [65536 .. 98303]    expert_decisions [rows]   (0/1, "both experts kept")
//   [98304]             gating_loss scalar
//
// E=2 algebra: softmax depends only on hd = h1-h0. p_max = 1/(1+exp(-|hd|))
// (identical formula to the reference's max-subtracted softmax), entropy =
// log1p(e) + p_min*|hd| (eps=1e-10 effect < 1e-9, far under threshold).

constexpr int D = 1024;
constexpr int ROWS = 32768;
constexpr int OUT_DEC = ROWS * 2;   // 65536
constexpr int OUT_LOSS = ROWS * 3;  // 98304
constexpr int BLOCKS = 2048;        // 8192 waves x 4 consecutive rows each

static __device__ __forceinline__ float softplusf(float v) {
    // logaddexp(v, 0) = max(v,0) + log1p(exp(-|v|))  (matches jax.nn.softplus)
    return fmaxf(v, 0.0f) + log1pf(expf(-fabsf(v)));
}

// Per-row epilogue given reduced d = c1-c0, n0, n1 and the row's noise pair.
// All lanes execute uniformly (inputs are wave-uniform after butterfly).
static __device__ __forceinline__ void row_epilogue(
    float d, float n0, float n1, float ns0, float ns1,
    double& imp0, double& imp1, double& entsum, float2& w, float& dec)
{
    float std0 = softplusf(n0) + 0.01f;
    float std1 = softplusf(n1) + 0.01f;
    float hd = d + ns1 * std1 - ns0 * std0;      // h1 - h0
    float ad = fabsf(hd);
    float e  = expf(-ad);                         // exp(h_min - h_max)
    float inv = 1.0f / (1.0f + e);
    float pmax = inv;                             // == reference's sorted p0
    float pmin = e * inv;
    float ent  = log1pf(e) + pmin * ad;           // -(l0 ln l0 + l1 ln l1)
    bool first   = (hd <= 0.0f);                  // l0 >= l1 (stable argsort tie)
    bool toponly = (pmax > 0.7f);                 // cum > TOP_P predicate
    imp0 += (double)pmax;
    if (!toponly) imp1 += (double)pmin;
    entsum += (double)ent;
    if (toponly) { w.x = first ? 1.f : 0.f; w.y = 1.f - w.x; dec = 0.f; }
    else         { w.x = 1.f; w.y = 1.f; dec = 1.f; }
}

__global__ __launch_bounds__(256) void router_main(
    const float* __restrict__ x,        // [ROWS, D]
    const float* __restrict__ gate_w,   // [2, D]
    const float* __restrict__ noise_w,  // [2, D]
    const float* __restrict__ ns,       // [ROWS, 2]
    float* __restrict__ out,            // [ROWS*3 + 1]
    double* __restrict__ part)          // [BLOCKS*3] per-block partials
{
    const int lane = threadIdx.x & 63;
    const int wid  = threadIdx.x >> 6;            // wave in block (0..3)
    const int wave = blockIdx.x * 4 + wid;        // 0..8191
    const int r0   = wave * 4;                    // 4 consecutive rows per wave
    const int base = lane * 16;                   // 64 lanes x 16 floats = D

    // Per-lane register slices: wd = gate_w[1]-gate_w[0], noise rows as-is.
    float4 wd[4], wn0[4], wn1[4];
#pragma unroll
    for (int i = 0; i < 4; ++i) {
        float4 g0 = *(const float4*)(gate_w + base + 4 * i);
        float4 g1 = *(const float4*)(gate_w + D + base + 4 * i);
        wd[i] = make_float4(g1.x - g0.x, g1.y - g0.y, g1.z - g0.z, g1.w - g0.w);
        wn0[i] = *(const float4*)(noise_w + base + 4 * i);
        wn1[i] = *(const float4*)(noise_w + D + base + 4 * i);
    }

    // Noise samples for the 4 rows (wave-uniform broadcast loads).
    float4 nsA = *(const float4*)(ns + 8 * (size_t)wave);      // rows r0, r0+1
    float4 nsB = *(const float4*)(ns + 8 * (size_t)wave + 4);  // rows r0+2, r0+3

    double imp0 = 0.0, imp1 = 0.0, entsum = 0.0;
    float2 w01[4];
    float  dec[4];

#pragma unroll
    for (int p = 0; p < 2; ++p) {                 // two pairs of rows
        const float* xa = x + (size_t)(r0 + 2 * p) * D + base;
        const float* xb = xa + D;
        float4 va[4], vb[4];
#pragma unroll
        for (int i = 0; i < 4; ++i) va[i] = *(const float4*)(xa + 4 * i);
#pragma unroll
        for (int i = 0; i < 4; ++i) vb[i] = *(const float4*)(xb + 4 * i);

        float da = 0.f, n0a = 0.f, n1a = 0.f, db = 0.f, n0b = 0.f, n1b = 0.f;
#pragma unroll
        for (int i = 0; i < 4; ++i) {
            da  = fmaf(va[i].x, wd[i].x,  fmaf(va[i].y, wd[i].y,  fmaf(va[i].z, wd[i].z,  fmaf(va[i].w, wd[i].w,  da))));
            n0a = fmaf(va[i].x, wn0[i].x, fmaf(va[i].y, wn0[i].y, fmaf(va[i].z, wn0[i].z, fmaf(va[i].w, wn0[i].w, n0a))));
            n1a = fmaf(va[i].x, wn1[i].x, fmaf(va[i].y, wn1[i].y, fmaf(va[i].z, wn1[i].z, fmaf(va[i].w, wn1[i].w, n1a))));
            db  = fmaf(vb[i].x, wd[i].x,  fmaf(vb[i].y, wd[i].y,  fmaf(vb[i].z, wd[i].z,  fmaf(vb[i].w, wd[i].w,  db))));
            n0b = fmaf(vb[i].x, wn0[i].x, fmaf(vb[i].y, wn0[i].y, fmaf(vb[i].z, wn0[i].z, fmaf(vb[i].w, wn0[i].w, n0b))));
            n1b = fmaf(vb[i].x, wn1[i].x, fmaf(vb[i].y, wn1[i].y, fmaf(vb[i].z, wn1[i].z, fmaf(vb[i].w, wn1[i].w, n1b))));
        }
        // 64-lane butterfly; results broadcast to all lanes.
#pragma unroll
        for (int off = 32; off; off >>= 1) {
            da  += __shfl_xor(da, off);
            n0a += __shfl_xor(n0a, off);
            n1a += __shfl_xor(n1a, off);
            db  += __shfl_xor(db, off);
            n0b += __shfl_xor(n0b, off);
            n1b += __shfl_xor(n1b, off);
        }
        float nsa0 = p ? nsB.x : nsA.x, nsa1 = p ? nsB.y : nsA.y;
        float nsb0 = p ? nsB.z : nsA.z, nsb1 = p ? nsB.w : nsA.w;
        row_epilogue(da, n0a, n1a, nsa0, nsa1, imp0, imp1, entsum, w01[2 * p], dec[2 * p]);
        row_epilogue(db, n0b, n1b, nsb0, nsb1, imp0, imp1, entsum, w01[2 * p + 1], dec[2 * p + 1]);
    }

    if (lane == 0) {
        // rows r0..r0+3: weights = 8 consecutive floats, decisions = 4.
        *(float4*)(out + 8 * (size_t)wave)     = make_float4(w01[0].x, w01[0].y, w01[1].x, w01[1].y);
        *(float4*)(out + 8 * (size_t)wave + 4) = make_float4(w01[2].x, w01[2].y, w01[3].x, w01[3].y);
        *(float4*)(out + OUT_DEC + 4 * (size_t)wave) = make_float4(dec[0], dec[1], dec[2], dec[3]);
    }

    // Block-level reduction of per-wave partials; ONE plain store per block.
    __shared__ double sred[4][3];
    if (lane == 0) {
        sred[wid][0] = imp0; sred[wid][1] = imp1; sred[wid][2] = entsum;
    }
    __syncthreads();
    if (threadIdx.x == 0) {
        double a = 0, b = 0, e = 0;
#pragma unroll
        for (int w = 0; w < 4; ++w) { a += sred[w][0]; b += sred[w][1]; e += sred[w][2]; }
        part[3 * (size_t)blockIdx.x + 0] = a;
        part[3 * (size_t)blockIdx.x + 1] = b;
        part[3 * (size_t)blockIdx.x + 2] = e;
    }
}

__global__ __launch_bounds__(256) void router_final(const double* __restrict__ part,
                                                    float* __restrict__ out) {
    const int lane = threadIdx.x & 63;
    const int wid  = threadIdx.x >> 6;
    double s0 = 0, s1 = 0, s2 = 0;
    for (int i = threadIdx.x; i < BLOCKS; i += 256) {
        s0 += part[3 * i + 0];
        s1 += part[3 * i + 1];
        s2 += part[3 * i + 2];
    }
#pragma unroll
    for (int off = 32; off; off >>= 1) {
        s0 += __shfl_xor(s0, off);
        s1 += __shfl_xor(s1, off);
        s2 += __shfl_xor(s2, off);
    }
    __shared__ double sl[4][3];
    if (lane == 0) { sl[wid][0] = s0; sl[wid][1] = s1; sl[wid][2] = s2; }
    __syncthreads();
    if (threadIdx.x == 0) {
        double a = 0, b = 0, ent = 0;
#pragma unroll
        for (int w = 0; w < 4; ++w) { a += sl[w][0]; b += sl[w][1]; ent += sl[w][2]; }
        double mean = 0.5 * (a + b);
        double var  = 0.5 * (a - b) * (a - b);   // ddof=1, E=2
        double li   = var / (mean * mean + 1e-10);
        double ld   = ent / (double)ROWS;
        out[OUT_LOSS] = (float)(li + 0.1 * ld);
    }
}

extern "C" void kernel_launch(void* const* d_in, const int* in_sizes, int n_in,
                              void* d_out, int out_size, void* d_ws, size_t ws_size,
                              hipStream_t stream) {
    const float* x       = (const float*)d_in[0];
    const float* gate_w  = (const float*)d_in[1];
    const float* noise_w = (const float*)d_in[2];
    const float* ns      = (const float*)d_in[3];
    float*  out  = (float*)d_out;
    double* part = (double*)d_ws;   // BLOCKS*3 doubles = 48 KiB

    router_main<<<BLOCKS, 256, 0, stream>>>(x, gate_w, noise_w, ns, out, part);
    router_final<<<1, 256, 0, stream>>>(part, out);
}

// Round 5
// 38.924 us; speedup vs baseline: 1.0267x; 1.0267x over previous
//
#include <hip/hip_runtime.h>
#include <math.h>

// ExpertRouter: B=8, N=4096, D=1024, E=2  -> rows = 32768
// Outputs (concatenated float32):
//   [0 .. 65535]        expert_weights  [rows,2]  (0/1)
//   [65536 .. 98303]    expert_decisions [rows]   (0/1, "both experts kept")
//   [98304]             gating_loss scalar
//
// E=2 algebra: softmax depends only on hd = h1-h0. p_max = 1/(1+exp(-|hd|))
// (identical formula to the reference's max-subtracted softmax), entropy =
// log1p(e) + p_min*|hd|.
//
// R5 changes vs R4:
//  * unit-stride lane mapping (256*i + 4*lane) for x and weights: each float4
//    load covers a contiguous 1KiB span (8 fully-used 128B lines) instead of
//    stride-64B (32 lines at 32B each).
//  * epilogue dedup: run the transcendental-heavy epilogue ONCE with lane r
//    handling row r (was 4 sequential uniform executions).

constexpr int D = 1024;
constexpr int ROWS = 32768;
constexpr int OUT_DEC = ROWS * 2;   // 65536
constexpr int OUT_LOSS = ROWS * 3;  // 98304
constexpr int BLOCKS = 2048;        // 8192 waves x 4 consecutive rows each

static __device__ __forceinline__ float softplusf(float v) {
    // logaddexp(v, 0) = max(v,0) + log1p(exp(-|v|))  (matches jax.nn.softplus)
    return fmaxf(v, 0.0f) + log1pf(expf(-fabsf(v)));
}

__global__ __launch_bounds__(256) void router_main(
    const float* __restrict__ x,        // [ROWS, D]
    const float* __restrict__ gate_w,   // [2, D]
    const float* __restrict__ noise_w,  // [2, D]
    const float* __restrict__ ns,       // [ROWS, 2]
    float* __restrict__ out,            // [ROWS*3 + 1]
    double* __restrict__ part)          // [BLOCKS*3] per-block partials
{
    const int lane = threadIdx.x & 63;
    const int wid  = threadIdx.x >> 6;            // wave in block (0..3)
    const int wave = blockIdx.x * 4 + wid;        // 0..8191
    const int r0   = wave * 4;                    // 4 consecutive rows per wave
    const int off  = 4 * lane;                    // unit-stride float4 mapping

    // Per-lane register slices: wd = gate_w[1]-gate_w[0], noise rows as-is.
    // Element set per (i,lane): floats [256*i + 4*lane .. +4) — same mapping
    // for weights and x, so the dot product pairing is consistent.
    float4 wd[4], wn0[4], wn1[4];
#pragma unroll
    for (int i = 0; i < 4; ++i) {
        float4 g0 = *(const float4*)(gate_w + 256 * i + off);
        float4 g1 = *(const float4*)(gate_w + D + 256 * i + off);
        wd[i] = make_float4(g1.x - g0.x, g1.y - g0.y, g1.z - g0.z, g1.w - g0.w);
        wn0[i] = *(const float4*)(noise_w + 256 * i + off);
        wn1[i] = *(const float4*)(noise_w + D + 256 * i + off);
    }

    // Noise samples for the 4 rows (wave-uniform broadcast loads).
    float4 nsA = *(const float4*)(ns + 8 * (size_t)wave);      // rows r0, r0+1
    float4 nsB = *(const float4*)(ns + 8 * (size_t)wave + 4);  // rows r0+2, r0+3

    float dS[4], n0S[4], n1S[4];

#pragma unroll
    for (int p = 0; p < 2; ++p) {                 // two pairs of rows
        const float* xa = x + (size_t)(r0 + 2 * p) * D + off;
        const float* xb = xa + D;
        float4 va[4], vb[4];
#pragma unroll
        for (int i = 0; i < 4; ++i) va[i] = *(const float4*)(xa + 256 * i);
#pragma unroll
        for (int i = 0; i < 4; ++i) vb[i] = *(const float4*)(xb + 256 * i);

        float da = 0.f, n0a = 0.f, n1a = 0.f, db = 0.f, n0b = 0.f, n1b = 0.f;
#pragma unroll
        for (int i = 0; i < 4; ++i) {
            da  = fmaf(va[i].x, wd[i].x,  fmaf(va[i].y, wd[i].y,  fmaf(va[i].z, wd[i].z,  fmaf(va[i].w, wd[i].w,  da))));
            n0a = fmaf(va[i].x, wn0[i].x, fmaf(va[i].y, wn0[i].y, fmaf(va[i].z, wn0[i].z, fmaf(va[i].w, wn0[i].w, n0a))));
            n1a = fmaf(va[i].x, wn1[i].x, fmaf(va[i].y, wn1[i].y, fmaf(va[i].z, wn1[i].z, fmaf(va[i].w, wn1[i].w, n1a))));
            db  = fmaf(vb[i].x, wd[i].x,  fmaf(vb[i].y, wd[i].y,  fmaf(vb[i].z, wd[i].z,  fmaf(vb[i].w, wd[i].w,  db))));
            n0b = fmaf(vb[i].x, wn0[i].x, fmaf(vb[i].y, wn0[i].y, fmaf(vb[i].z, wn0[i].z, fmaf(vb[i].w, wn0[i].w, n0b))));
            n1b = fmaf(vb[i].x, wn1[i].x, fmaf(vb[i].y, wn1[i].y, fmaf(vb[i].z, wn1[i].z, fmaf(vb[i].w, wn1[i].w, n1b))));
        }
        // 64-lane butterfly; results broadcast to all lanes.
#pragma unroll
        for (int o = 32; o; o >>= 1) {
            da  += __shfl_xor(da, o);
            n0a += __shfl_xor(n0a, o);
            n1a += __shfl_xor(n1a, o);
            db  += __shfl_xor(db, o);
            n0b += __shfl_xor(n0b, o);
            n1b += __shfl_xor(n1b, o);
        }
        dS[2 * p] = da;  n0S[2 * p] = n0a;  n1S[2 * p] = n1a;
        dS[2 * p + 1] = db;  n0S[2 * p + 1] = n0b;  n1S[2 * p + 1] = n1b;
    }

    // ---- Deduplicated epilogue: lane r computes row r (r = lane & 3). ----
    // All 12 sums are wave-uniform registers; select via cndmask ternaries
    // (constant indices only — no runtime array indexing).
    const int r = lane & 3;
    float d  = (r == 0) ? dS[0]  : (r == 1) ? dS[1]  : (r == 2) ? dS[2]  : dS[3];
    float n0 = (r == 0) ? n0S[0] : (r == 1) ? n0S[1] : (r == 2) ? n0S[2] : n0S[3];
    float n1 = (r == 0) ? n1S[0] : (r == 1) ? n1S[1] : (r == 2) ? n1S[2] : n1S[3];
    float ns0 = (r == 0) ? nsA.x : (r == 1) ? nsA.z : (r == 2) ? nsB.x : nsB.z;
    float ns1 = (r == 0) ? nsA.y : (r == 1) ? nsA.w : (r == 2) ? nsB.y : nsB.w;

    float std0 = softplusf(n0) + 0.01f;
    float std1 = softplusf(n1) + 0.01f;
    float hd = d + ns1 * std1 - ns0 * std0;       // h1 - h0
    float ad = fabsf(hd);
    float e  = expf(-ad);                          // exp(h_min - h_max)
    float inv = 1.0f / (1.0f + e);
    float pmax = inv;                              // == reference's sorted p0
    float pmin = e * inv;
    float ent  = log1pf(e) + pmin * ad;            // -(l0 ln l0 + l1 ln l1)
    bool first   = (hd <= 0.0f);                   // l0 >= l1 (stable argsort)
    bool toponly = (pmax > 0.7f);                  // cum > TOP_P predicate

    double imp0 = (double)pmax;
    double imp1 = toponly ? 0.0 : (double)pmin;
    double entd = (double)ent;

    // Stores: lanes 0..3 hold rows r0..r0+3 (lanes 4+ are replicas, masked off).
    if (lane < 4) {
        float w0, w1;
        if (toponly) { w0 = first ? 1.f : 0.f; w1 = 1.f - w0; }
        else         { w0 = 1.f; w1 = 1.f; }
        *(float2*)(out + 8 * (size_t)wave + 2 * r) = make_float2(w0, w1);
        out[OUT_DEC + 4 * (size_t)wave + r] = toponly ? 0.f : 1.f;
    }

    // Wave totals: sum lanes 0..3 (xor-1 then xor-2), result on lane 0.
    imp0 += __shfl_xor(imp0, 1);  imp1 += __shfl_xor(imp1, 1);  entd += __shfl_xor(entd, 1);
    imp0 += __shfl_xor(imp0, 2);  imp1 += __shfl_xor(imp1, 2);  entd += __shfl_xor(entd, 2);

    // Block-level reduction of per-wave partials; ONE plain store per block.
    __shared__ double sred[4][3];
    if (lane == 0) {
        sred[wid][0] = imp0; sred[wid][1] = imp1; sred[wid][2] = entd;
    }
    __syncthreads();
    if (threadIdx.x == 0) {
        double a = 0, b = 0, e2 = 0;
#pragma unroll
        for (int w = 0; w < 4; ++w) { a += sred[w][0]; b += sred[w][1]; e2 += sred[w][2]; }
        part[3 * (size_t)blockIdx.x + 0] = a;
        part[3 * (size_t)blockIdx.x + 1] = b;
        part[3 * (size_t)blockIdx.x + 2] = e2;
    }
}

__global__ __launch_bounds__(256) void router_final(const double* __restrict__ part,
                                                    float* __restrict__ out) {
    const int lane = threadIdx.x & 63;
    const int wid  = threadIdx.x >> 6;
    double s0 = 0, s1 = 0, s2 = 0;
    for (int i = threadIdx.x; i < BLOCKS; i += 256) {
        s0 += part[3 * i + 0];
        s1 += part[3 * i + 1];
        s2 += part[3 * i + 2];
    }
#pragma unroll
    for (int o = 32; o; o >>= 1) {
        s0 += __shfl_xor(s0, o);
        s1 += __shfl_xor(s1, o);
        s2 += __shfl_xor(s2, o);
    }
    __shared__ double sl[4][3];
    if (lane == 0) { sl[wid][0] = s0; sl[wid][1] = s1; sl[wid][2] = s2; }
    __syncthreads();
    if (threadIdx.x == 0) {
        double a = 0, b = 0, ent = 0;
#pragma unroll
        for (int w = 0; w < 4; ++w) { a += sl[w][0]; b += sl[w][1]; ent += sl[w][2]; }
        double mean = 0.5 * (a + b);
        double var  = 0.5 * (a - b) * (a - b);   // ddof=1, E=2
        double li   = var / (mean * mean + 1e-10);
        double ld   = ent / (double)ROWS;
        out[OUT_LOSS] = (float)(li + 0.1 * ld);
    }
}

extern "C" void kernel_launch(void* const* d_in, const int* in_sizes, int n_in,
                              void* d_out, int out_size, void* d_ws, size_t ws_size,
                              hipStream_t stream) {
    const float* x       = (const float*)d_in[0];
    const float* gate_w  = (const float*)d_in[1];
    const float* noise_w = (const float*)d_in[2];
    const float* ns      = (const float*)d_in[3];
    float*  out  = (float*)d_out;
    double* part = (double*)d_ws;   // BLOCKS*3 doubles = 48 KiB

    router_main<<<BLOCKS, 256, 0, stream>>>(x, gate_w, noise_w, ns, out, part);
    router_final<<<1, 256, 0, stream>>>(part, out);
}

// Round 6
// 30.992 us; speedup vs baseline: 1.2895x; 1.2560x over previous
//
#include <hip/hip_runtime.h>
#include <math.h>

// ExpertRouter: B=8, N=4096, D=1024, E=2  -> rows = 32768
// Outputs (concatenated float32):
//   [0 .. 65535]        expert_weights  [rows,2]  (0/1)
//   [65536 .. 98303]    expert_decisions [rows]   (0/1, "both experts kept")
//   [98304]             gating_loss scalar
//
// R6 structure: weights staged in LDS (frees ~48 VGPR/lane), 2 rows per wave
// with all 8 x-float4 loads issued up-front (single latency exposure/wave),
// 16384 waves for maximum chip-wide read MLP. Decisive probe: if this doesn't
// move the needle, the x-read path (~4.3 TB/s observed) is the ceiling.

constexpr int D = 1024;
constexpr int ROWS = 32768;
constexpr int OUT_DEC = ROWS * 2;   // 65536
constexpr int OUT_LOSS = ROWS * 3;  // 98304
constexpr int BLOCKS = 4096;        // 16384 waves x 2 consecutive rows each

static __device__ __forceinline__ float softplusf(float v) {
    // logaddexp(v, 0) = max(v,0) + log1p(exp(-|v|))  (matches jax.nn.softplus)
    return fmaxf(v, 0.0f) + log1pf(expf(-fabsf(v)));
}

__global__ __launch_bounds__(256) void router_main(
    const float* __restrict__ x,        // [ROWS, D]
    const float* __restrict__ gate_w,   // [2, D]
    const float* __restrict__ noise_w,  // [2, D]
    const float* __restrict__ ns,       // [ROWS, 2]
    float* __restrict__ out,            // [ROWS*3 + 1]
    double* __restrict__ part)          // [BLOCKS*3] per-block partials
{
    const int t    = threadIdx.x;
    const int lane = t & 63;
    const int wid  = t >> 6;                      // wave in block (0..3)
    const int wave = blockIdx.x * 4 + wid;        // 0..16383
    const int r0   = wave * 2;                    // 2 consecutive rows per wave

    // ---- Stage folded weights in LDS: wd = g1-g0, wn0, wn1 (3 KiB). ----
    // Thread t owns float4 #t of each 1024-float vector.
    __shared__ float4 swd[256], swn0[256], swn1[256];
    {
        const float4* g4 = (const float4*)gate_w;
        const float4* n4 = (const float4*)noise_w;
        float4 g0 = g4[t], g1 = g4[256 + t];
        swd[t]  = make_float4(g1.x - g0.x, g1.y - g0.y, g1.z - g0.z, g1.w - g0.w);
        swn0[t] = n4[t];
        swn1[t] = n4[256 + t];
    }
    __syncthreads();

    // ---- Issue ALL x loads up-front: 2 rows x 4 float4 (unit-stride). ----
    const float4* xa4 = (const float4*)(x + (size_t)r0 * D);
    const float4* xb4 = xa4 + 256;
    float4 va[4], vb[4];
#pragma unroll
    for (int i = 0; i < 4; ++i) va[i] = xa4[64 * i + lane];
#pragma unroll
    for (int i = 0; i < 4; ++i) vb[i] = xb4[64 * i + lane];

    // Noise samples for rows r0, r0+1 (wave-uniform broadcast load).
    float4 nsv = *(const float4*)(ns + 4 * (size_t)wave);

    float da = 0.f, n0a = 0.f, n1a = 0.f, db = 0.f, n0b = 0.f, n1b = 0.f;
#pragma unroll
    for (int i = 0; i < 4; ++i) {
        float4 wdv = swd[64 * i + lane];
        float4 w0v = swn0[64 * i + lane];
        float4 w1v = swn1[64 * i + lane];
        da  = fmaf(va[i].x, wdv.x, fmaf(va[i].y, wdv.y, fmaf(va[i].z, wdv.z, fmaf(va[i].w, wdv.w, da))));
        n0a = fmaf(va[i].x, w0v.x, fmaf(va[i].y, w0v.y, fmaf(va[i].z, w0v.z, fmaf(va[i].w, w0v.w, n0a))));
        n1a = fmaf(va[i].x, w1v.x, fmaf(va[i].y, w1v.y, fmaf(va[i].z, w1v.z, fmaf(va[i].w, w1v.w, n1a))));
        db  = fmaf(vb[i].x, wdv.x, fmaf(vb[i].y, wdv.y, fmaf(vb[i].z, wdv.z, fmaf(vb[i].w, wdv.w, db))));
        n0b = fmaf(vb[i].x, w0v.x, fmaf(vb[i].y, w0v.y, fmaf(vb[i].z, w0v.z, fmaf(vb[i].w, w0v.w, n0b))));
        n1b = fmaf(vb[i].x, w1v.x, fmaf(vb[i].y, w1v.y, fmaf(vb[i].z, w1v.z, fmaf(vb[i].w, w1v.w, n1b))));
    }
    // 64-lane butterfly; results broadcast to all lanes.
#pragma unroll
    for (int o = 32; o; o >>= 1) {
        da  += __shfl_xor(da, o);
        n0a += __shfl_xor(n0a, o);
        n1a += __shfl_xor(n1a, o);
        db  += __shfl_xor(db, o);
        n0b += __shfl_xor(n0b, o);
        n1b += __shfl_xor(n1b, o);
    }

    // ---- Epilogue once: lane r (r = lane & 1) computes row r0+r. ----
    const int r = lane & 1;
    float d   = r ? db  : da;
    float n0  = r ? n0b : n0a;
    float n1  = r ? n1b : n1a;
    float ns0 = r ? nsv.z : nsv.x;
    float ns1 = r ? nsv.w : nsv.y;

    float std0 = softplusf(n0) + 0.01f;
    float std1 = softplusf(n1) + 0.01f;
    float hd = d + ns1 * std1 - ns0 * std0;       // h1 - h0
    float ad = fabsf(hd);
    float e  = expf(-ad);                          // exp(h_min - h_max)
    float inv = 1.0f / (1.0f + e);
    float pmax = inv;                              // == reference's sorted p0
    float pmin = e * inv;
    float ent  = log1pf(e) + pmin * ad;            // -(l0 ln l0 + l1 ln l1)
    bool first   = (hd <= 0.0f);                   // l0 >= l1 (stable argsort)
    bool toponly = (pmax > 0.7f);                  // cum > TOP_P predicate

    double imp0 = (double)pmax;
    double imp1 = toponly ? 0.0 : (double)pmin;
    double entd = (double)ent;

    // Stores: lanes 0,1 hold rows r0, r0+1.
    if (lane < 2) {
        float w0, w1;
        if (toponly) { w0 = first ? 1.f : 0.f; w1 = 1.f - w0; }
        else         { w0 = 1.f; w1 = 1.f; }
        *(float2*)(out + 4 * (size_t)wave + 2 * r) = make_float2(w0, w1);
        out[OUT_DEC + 2 * (size_t)wave + r] = toponly ? 0.f : 1.f;
    }

    // Wave totals: sum lanes 0,1 (xor-1); lane 0 holds the wave partial.
    imp0 += __shfl_xor(imp0, 1);
    imp1 += __shfl_xor(imp1, 1);
    entd += __shfl_xor(entd, 1);

    // Block-level reduction of per-wave partials; ONE plain store per block.
    __shared__ double sred[4][3];
    if (lane == 0) {
        sred[wid][0] = imp0; sred[wid][1] = imp1; sred[wid][2] = entd;
    }
    __syncthreads();
    if (t == 0) {
        double a = 0, b = 0, e2 = 0;
#pragma unroll
        for (int w = 0; w < 4; ++w) { a += sred[w][0]; b += sred[w][1]; e2 += sred[w][2]; }
        part[3 * (size_t)blockIdx.x + 0] = a;
        part[3 * (size_t)blockIdx.x + 1] = b;
        part[3 * (size_t)blockIdx.x + 2] = e2;
    }
}

__global__ __launch_bounds__(1024) void router_final(const double* __restrict__ part,
                                                     float* __restrict__ out) {
    const int t    = threadIdx.x;
    const int lane = t & 63;
    const int wid  = t >> 6;                      // 16 waves
    double s0 = 0, s1 = 0, s2 = 0;
#pragma unroll
    for (int i = t; i < BLOCKS; i += 1024) {      // 4 iterations
        s0 += part[3 * i + 0];
        s1 += part[3 * i + 1];
        s2 += part[3 * i + 2];
    }
#pragma unroll
    for (int o = 32; o; o >>= 1) {
        s0 += __shfl_xor(s0, o);
        s1 += __shfl_xor(s1, o);
        s2 += __shfl_xor(s2, o);
    }
    __shared__ double sl[16][3];
    if (lane == 0) { sl[wid][0] = s0; sl[wid][1] = s1; sl[wid][2] = s2; }
    __syncthreads();
    if (t == 0) {
        double a = 0, b = 0, ent = 0;
#pragma unroll
        for (int w = 0; w < 16; ++w) { a += sl[w][0]; b += sl[w][1]; ent += sl[w][2]; }
        double mean = 0.5 * (a + b);
        double var  = 0.5 * (a - b) * (a - b);   // ddof=1, E=2
        double li   = var / (mean * mean + 1e-10);
        double ld   = ent / (double)ROWS;
        out[OUT_LOSS] = (float)(li + 0.1 * ld);
    }
}

extern "C" void kernel_launch(void* const* d_in, const int* in_sizes, int n_in,
                              void* d_out, int out_size, void* d_ws, size_t ws_size,
                              hipStream_t stream) {
    const float* x       = (const float*)d_in[0];
    const float* gate_w  = (const float*)d_in[1];
    const float* noise_w = (const float*)d_in[2];
    const float* ns      = (const float*)d_in[3];
    float*  out  = (float*)d_out;
    double* part = (double*)d_ws;   // BLOCKS*3 doubles = 96 KiB

    router_main<<<BLOCKS, 256, 0, stream>>>(x, gate_w, noise_w, ns, out, part);
    router_final<<<1, 1024, 0, stream>>>(part, out);
}